// Round 1
// baseline (613.608 us; speedup 1.0000x reference)
//
#include <hip/hip_runtime.h>
#include <hip/hip_bf16.h>
#include <math.h>

typedef _Float16 half8_t __attribute__((ext_vector_type(8)));
typedef _Float16 half4_t __attribute__((ext_vector_type(4)));
typedef float    floatx4 __attribute__((ext_vector_type(4)));

#define GLOAD16(gp, lp) __builtin_amdgcn_global_load_lds( \
    (const __attribute__((address_space(1))) void*)(gp),  \
    (__attribute__((address_space(3))) void*)(lp), 16, 0, 0)

static constexpr int Bc  = 8;
static constexpr int Tc  = 4096;
static constexpr int Ic  = 1024;   // input dim (GEMM K)
static constexpr int Hc  = 1024;   // hidden dim (GEMM N)
static constexpr int Mc  = Bc * Tc;      // 32768 GEMM rows
static constexpr int NCc = 64;           // scan chunks
static constexpr int Lc  = Tc / NCc;     // 64 steps per chunk

// ---------------- fp32 -> fp16 convert ----------------
__global__ void cvt_kernel(const float* __restrict__ in, _Float16* __restrict__ out, long n)
{
    long i = ((long)blockIdx.x * blockDim.x + threadIdx.x) * 4;
    long stride = (long)gridDim.x * blockDim.x * 4;
    for (; i < n; i += stride) {
        float4 v = *reinterpret_cast<const float4*>(in + i);
        half4_t h;
        h[0] = (_Float16)v.x; h[1] = (_Float16)v.y;
        h[2] = (_Float16)v.z; h[3] = (_Float16)v.w;
        *reinterpret_cast<half4_t*>(out + i) = h;
    }
}

// ---------------- dual GEMM (fp16 MFMA, NT layout) ----------------
// A: [M, K] fp16 row-major (x), Bw: [N, K] fp16 row-major (W),
// C = A * Bw^T + bias, stored fp32 [M, N].  blockIdx.z selects {Wz,bz,Ck} vs {Wh,bh,Cp}.
__global__ __launch_bounds__(256) void dual_gemm_f16(
    const _Float16* __restrict__ A,
    const _Float16* __restrict__ Wz,
    const _Float16* __restrict__ Wh,
    const float* __restrict__ bz,
    const float* __restrict__ bh,
    float* __restrict__ Ck,
    float* __restrict__ Cp)
{
    constexpr int BM = 128, BN = 128, BK = 32, K = Ic, N = Hc;
    __shared__ __align__(16) _Float16 sA[BM * BK];
    __shared__ __align__(16) _Float16 sB[BN * BK];

    const _Float16* Bw  = blockIdx.z ? Wh : Wz;
    const float*   bias = blockIdx.z ? bh : bz;
    float*         C    = blockIdx.z ? Cp : Ck;

    const int tid  = threadIdx.x;
    const int lane = tid & 63;
    const int wave = tid >> 6;
    const int wr = wave >> 1, wc = wave & 1;     // 2x2 waves, 64x64 each
    const int m0 = blockIdx.y * BM, n0 = blockIdx.x * BN;

    // staging: thread i -> tile row i>>2 (0..63), 8-half chunk i&3; two issues cover 128 rows
    const int srow = tid >> 2;
    const int schk = (tid & 3) * 8;
    const _Float16* gA = A  + (size_t)(m0 + srow) * K + schk;
    const _Float16* gB = Bw + (size_t)(n0 + srow) * K + schk;
    _Float16* lA = &sA[srow * BK + schk];
    _Float16* lB = &sB[srow * BK + schk];

    // MFMA fragment read addresses (16x16x32: A row=lane&15, k=(lane>>4)*8)
    const int lrow = lane & 15;
    const int kch  = (lane >> 4) * 8;
    const half8_t* rA = (const half8_t*)&sA[(wr * 64 + lrow) * BK + kch];
    const half8_t* rB = (const half8_t*)&sB[(wc * 64 + lrow) * BK + kch];

    floatx4 zero4 = {0.f, 0.f, 0.f, 0.f};
    floatx4 acc[4][4];
#pragma unroll
    for (int m = 0; m < 4; m++)
#pragma unroll
        for (int n = 0; n < 4; n++) acc[m][n] = zero4;

    for (int kt = 0; kt < K; kt += BK) {
        GLOAD16(gA + kt,                  lA);
        GLOAD16(gA + kt + (size_t)64 * K, lA + 64 * BK);
        GLOAD16(gB + kt,                  lB);
        GLOAD16(gB + kt + (size_t)64 * K, lB + 64 * BK);
        __syncthreads();   // drains global_load_lds (vmcnt) + barrier

        half8_t af[4], bf[4];
#pragma unroll
        for (int m = 0; m < 4; m++) af[m] = rA[m * 64];   // m*16 rows * 32 halfs / 8
#pragma unroll
        for (int n = 0; n < 4; n++) bf[n] = rB[n * 64];
#pragma unroll
        for (int m = 0; m < 4; m++)
#pragma unroll
            for (int n = 0; n < 4; n++)
                acc[m][n] = __builtin_amdgcn_mfma_f32_16x16x32_f16(af[m], bf[n], acc[m][n], 0, 0, 0);
        __syncthreads();   // protect LDS from next iteration's staging
    }

    // epilogue: D row=(lane>>4)*4+reg, col=lane&15 (per 16x16 fragment)
    const int r0 = (lane >> 4) * 4;
#pragma unroll
    for (int n = 0; n < 4; n++) {
        const int col = n0 + wc * 64 + n * 16 + lrow;
        const float bv = bias[col];
#pragma unroll
        for (int m = 0; m < 4; m++) {
            const int row = m0 + wr * 64 + m * 16 + r0;
#pragma unroll
            for (int r = 0; r < 4; r++)
                C[(size_t)(row + r) * N + col] = acc[m][n][r] + bv;
        }
    }
}

// ---------------- scan helpers ----------------
__device__ __forceinline__ float sigm(float x) { return 1.0f / (1.0f + expf(-x)); }
__device__ __forceinline__ float g_fn(float x) { return x >= 0.0f ? x + 0.5f : sigm(x); }
__device__ __forceinline__ void fv_from_kp(float kk, float pp, float& f, float& v)
{
    float ek = expf(kk);          // e^k
    f = 1.0f / (1.0f + ek);       // sigmoid(-k) = 1 - z
    float z = 1.0f - f;           // sigmoid(k)
    v = z * g_fn(pp);
}

// pass A: per (b, chunk, h): F = prod f, S = local scan with zero init
__global__ void scanA(const float* __restrict__ kb, const float* __restrict__ pb,
                      float* __restrict__ Fb, float* __restrict__ Sb)
{
    const int b = blockIdx.z, c = blockIdx.y;
    const int h = blockIdx.x * blockDim.x + threadIdx.x;
    size_t base = ((size_t)b * Tc + (size_t)c * Lc) * Hc + h;
    float F = 1.0f, S = 0.0f;
    for (int t = 0; t < Lc; t++) {
        float kk = kb[base + (size_t)t * Hc];
        float pp = pb[base + (size_t)t * Hc];
        float f, v; fv_from_kp(kk, pp, f, v);
        S = fmaf(f, S, v);
        F *= f;
    }
    size_t ci = ((size_t)b * NCc + c) * Hc + h;
    Fb[ci] = F; Sb[ci] = S;
}

// pass B: sequential carry scan over chunks (8192 channels)
__global__ void scanB(const float* __restrict__ h0, const float* __restrict__ Fb,
                      const float* __restrict__ Sb, float* __restrict__ Cin)
{
    const int idx = blockIdx.x * blockDim.x + threadIdx.x;  // 0..8191
    const int b = idx >> 10, h = idx & 1023;
    float carry = g_fn(h0[(size_t)b * Hc + h]);
    for (int c = 0; c < NCc; c++) {
        size_t ci = ((size_t)b * NCc + c) * Hc + h;
        Cin[ci] = carry;
        carry = fmaf(Fb[ci], carry, Sb[ci]);
    }
}

// pass C: apply carry, recompute f/v, write h
__global__ void scanC(const float* __restrict__ kb, const float* __restrict__ pb,
                      const float* __restrict__ Cin, float* __restrict__ out)
{
    const int b = blockIdx.z, c = blockIdx.y;
    const int h = blockIdx.x * blockDim.x + threadIdx.x;
    size_t base = ((size_t)b * Tc + (size_t)c * Lc) * Hc + h;
    float hr = Cin[((size_t)b * NCc + c) * Hc + h];
    for (int t = 0; t < Lc; t++) {
        float kk = kb[base + (size_t)t * Hc];
        float pp = pb[base + (size_t)t * Hc];
        float f, v; fv_from_kp(kk, pp, f, v);
        hr = fmaf(f, hr, v);
        out[base + (size_t)t * Hc] = hr;
    }
}

// ---------------- launch ----------------
extern "C" void kernel_launch(void* const* d_in, const int* in_sizes, int n_in,
                              void* d_out, int out_size, void* d_ws, size_t ws_size,
                              hipStream_t stream)
{
    const float* x  = (const float*)d_in[0];
    const float* h0 = (const float*)d_in[1];
    const float* Wz = (const float*)d_in[2];
    const float* bz = (const float*)d_in[3];
    const float* Wh = (const float*)d_in[4];
    const float* bh = (const float*)d_in[5];
    float* out = (float*)d_out;

    char* ws = (char*)d_ws;
    // layout (bytes): x16 67108864 | w16z 2097152 | w16h 2097152 | kbuf 134217728 |
    //                 pbuf 134217728 | Fb 2097152 | Sb 2097152 | Cin 2097152
    _Float16* x16  = (_Float16*)ws;
    _Float16* w16z = (_Float16*)(ws + 67108864);
    _Float16* w16h = w16z + (size_t)Hc * Ic;
    float* kbuf = (float*)(ws + 71303168);
    float* pbuf = (float*)(ws + 71303168 + 134217728);
    float* Fb   = (float*)(ws + 339738624ULL);
    float* Sb   = (float*)(ws + 341835776ULL);
    float* Cin  = (float*)(ws + 343932928ULL);

    cvt_kernel<<<2048, 256, 0, stream>>>(x,  x16,  (long)Mc * Ic);
    cvt_kernel<<<256,  256, 0, stream>>>(Wz, w16z, (long)Hc * Ic);
    cvt_kernel<<<256,  256, 0, stream>>>(Wh, w16h, (long)Hc * Ic);

    dim3 ggrid(Hc / 128, Mc / 128, 2);   // (8, 256, 2)
    dual_gemm_f16<<<ggrid, 256, 0, stream>>>(x16, w16z, w16h, bz, bh, kbuf, pbuf);

    dim3 sgrid(Hc / 256, NCc, Bc);       // (4, 64, 8)
    scanA<<<sgrid, 256, 0, stream>>>(kbuf, pbuf, Fb, Sb);
    scanB<<<32, 256, 0, stream>>>(h0, Fb, Sb, Cin);
    scanC<<<sgrid, 256, 0, stream>>>(kbuf, pbuf, Cin, out);
}

// Round 2
// 504.064 us; speedup vs baseline: 1.2173x; 1.2173x over previous
//
#include <hip/hip_runtime.h>
#include <hip/hip_bf16.h>
#include <math.h>

typedef _Float16 half8_t __attribute__((ext_vector_type(8)));
typedef _Float16 half4_t __attribute__((ext_vector_type(4)));
typedef float    floatx4 __attribute__((ext_vector_type(4)));

#define GLOAD16(gp, lp) __builtin_amdgcn_global_load_lds( \
    (const __attribute__((address_space(1))) void*)(gp),  \
    (__attribute__((address_space(3))) void*)(lp), 16, 0, 0)

static constexpr int Bc  = 8;
static constexpr int Tc  = 4096;
static constexpr int Ic  = 1024;     // GEMM K
static constexpr int Hc  = 1024;     // GEMM N
static constexpr int Mc  = Bc * Tc;  // 32768 GEMM rows
static constexpr int NC2 = 128;      // scan chunks
static constexpr int L2c = Tc / NC2; // 32 steps per chunk

// ---------------- fp32 -> fp16 convert ----------------
__global__ void cvt_kernel(const float* __restrict__ in, _Float16* __restrict__ out, long n)
{
    long i = ((long)blockIdx.x * blockDim.x + threadIdx.x) * 4;
    long stride = (long)gridDim.x * blockDim.x * 4;
    for (; i < n; i += stride) {
        float4 v = *reinterpret_cast<const float4*>(in + i);
        half4_t h;
        h[0] = (_Float16)v.x; h[1] = (_Float16)v.y;
        h[2] = (_Float16)v.z; h[3] = (_Float16)v.w;
        *reinterpret_cast<half4_t*>(out + i) = h;
    }
}

// ---------------- fused dual GEMM (fp16 MFMA, NT, dbuf prefetch) ----------------
// One block: 128 rows x 128 cols of BOTH outputs. A staged once per K-step.
// 8 waves: wave>>2 selects output (0:k, 1:p); (wave>>1)&1, wave&1 pick 64x64 sub-tile.
__global__ __launch_bounds__(512) void dual_gemm_f16(
    const _Float16* __restrict__ A,
    const _Float16* __restrict__ Wz,
    const _Float16* __restrict__ Wh,
    const float* __restrict__ bz,
    const float* __restrict__ bh,
    _Float16* __restrict__ k16,
    _Float16* __restrict__ p16)
{
    constexpr int BK = 32, K = Ic, N = Hc, NSTEP = K / BK;
    __shared__ __align__(16) _Float16 sA [2][128 * BK];
    __shared__ __align__(16) _Float16 sBz[2][128 * BK];
    __shared__ __align__(16) _Float16 sBh[2][128 * BK];

    // XCD-chunked swizzle: XCD x gets logical blocks [x*256,(x+1)*256) ->
    // all 8 n-blocks of an A-panel share one XCD's L2. 2048 % 8 == 0 -> bijective.
    const int bid     = blockIdx.x;
    const int logical = (bid & 7) * 256 + (bid >> 3);
    const int n0 = (logical & 7) * 128;
    const int m0 = (logical >> 3) * 128;

    const int tid  = threadIdx.x;
    const int lane = tid & 63;
    const int wave = tid >> 6;
    const int zsel = wave >> 2;
    const int wr = (wave >> 1) & 1, wc = wave & 1;

    // staging: thread i -> tile row i>>2 (0..127), 8-half chunk i&3
    const int srow = tid >> 2;
    const int schk = (tid & 3) * 8;
    const int soff = srow * BK + schk;
    const _Float16* gA  = A  + (size_t)(m0 + srow) * K + schk;
    const _Float16* gBz = Wz + (size_t)(n0 + srow) * K + schk;
    const _Float16* gBh = Wh + (size_t)(n0 + srow) * K + schk;

    // MFMA fragment addressing (16x16x32: row=lane&15, k-chunk=(lane>>4)*8)
    const int lrow = lane & 15;
    const int kch  = (lane >> 4) * 8;
    const _Float16* sBsel = zsel ? &sBh[0][0] : &sBz[0][0];
    const int aoff = (wr * 64 + lrow) * BK + kch;
    const int boff = (wc * 64 + lrow) * BK + kch;

    floatx4 acc[4][4];
#pragma unroll
    for (int m = 0; m < 4; m++)
#pragma unroll
        for (int n = 0; n < 4; n++) acc[m][n] = (floatx4){0.f, 0.f, 0.f, 0.f};

    // prologue: stage tile 0 into buf 0
    GLOAD16(gA,  &sA [0][soff]);
    GLOAD16(gBz, &sBz[0][soff]);
    GLOAD16(gBh, &sBh[0][soff]);
    __syncthreads();

    int buf = 0;
    for (int ki = 0; ki < NSTEP; ki++) {
        if (ki + 1 < NSTEP) {            // prefetch next tile into other buffer
            const int kt = (ki + 1) * BK;
            GLOAD16(gA  + kt, &sA [buf ^ 1][soff]);
            GLOAD16(gBz + kt, &sBz[buf ^ 1][soff]);
            GLOAD16(gBh + kt, &sBh[buf ^ 1][soff]);
        }
        const half8_t* rA = (const half8_t*)&sA[buf][aoff];
        const half8_t* rB = (const half8_t*)(sBsel + (size_t)buf * (128 * BK) + boff);
        half8_t af[4], bf[4];
#pragma unroll
        for (int m = 0; m < 4; m++) af[m] = rA[m * 64];   // +16 rows = 16*32/8 half8s
#pragma unroll
        for (int n = 0; n < 4; n++) bf[n] = rB[n * 64];
#pragma unroll
        for (int m = 0; m < 4; m++)
#pragma unroll
            for (int n = 0; n < 4; n++)
                acc[m][n] = __builtin_amdgcn_mfma_f32_16x16x32_f16(af[m], bf[n], acc[m][n], 0, 0, 0);
        __syncthreads();   // drains vmcnt (prefetch landed) + all LDS reads done
        buf ^= 1;
    }

    // epilogue: D row=(lane>>4)*4+reg, col=lane&15 per 16x16 fragment; fp16 store
    _Float16* C = zsel ? p16 : k16;
    const float* bias = zsel ? bh : bz;
    const int r0 = (lane >> 4) * 4;
#pragma unroll
    for (int n = 0; n < 4; n++) {
        const int col = n0 + wc * 64 + n * 16 + lrow;
        const float bv = bias[col];
#pragma unroll
        for (int m = 0; m < 4; m++) {
            const int row = m0 + wr * 64 + m * 16 + r0;
#pragma unroll
            for (int r = 0; r < 4; r++)
                C[(size_t)(row + r) * N + col] = (_Float16)(acc[m][n][r] + bv);
        }
    }
}

// ---------------- scan helpers ----------------
__device__ __forceinline__ float sigm(float x) { return 1.0f / (1.0f + __expf(-x)); }
__device__ __forceinline__ float g_fn(float x) { return x >= 0.0f ? x + 0.5f : sigm(x); }
__device__ __forceinline__ void fv_from_kp(float kk, float pp, float& f, float& v)
{
    float ek = __expf(kk);        // e^k
    f = 1.0f / (1.0f + ek);       // sigmoid(-k)
    float z = 1.0f - f;           // sigmoid(k)
    v = z * g_fn(pp);
}

// pass A: per (b, chunk): F = prod f, S = local scan (zero init). 8 h per thread.
__global__ __launch_bounds__(128) void scanA(const _Float16* __restrict__ k16,
                                             const _Float16* __restrict__ p16,
                                             float* __restrict__ Fb, float* __restrict__ Sb)
{
    const int b = blockIdx.y, c = blockIdx.x;
    const int h0 = threadIdx.x * 8;
    size_t base = ((size_t)b * Tc + (size_t)c * L2c) * Hc + h0;
    float F[8], S[8];
#pragma unroll
    for (int j = 0; j < 8; j++) { F[j] = 1.0f; S[j] = 0.0f; }
    for (int t = 0; t < L2c; t++) {
        half8_t k8 = *reinterpret_cast<const half8_t*>(k16 + base + (size_t)t * Hc);
        half8_t p8 = *reinterpret_cast<const half8_t*>(p16 + base + (size_t)t * Hc);
#pragma unroll
        for (int j = 0; j < 8; j++) {
            float f, v; fv_from_kp((float)k8[j], (float)p8[j], f, v);
            S[j] = fmaf(f, S[j], v);
            F[j] *= f;
        }
    }
    size_t ci = ((size_t)b * NC2 + c) * Hc + h0;
#pragma unroll
    for (int j = 0; j < 8; j++) { Fb[ci + j] = F[j]; Sb[ci + j] = S[j]; }
}

// pass B: sequential carry scan over chunks (8192 channels)
__global__ void scanB(const float* __restrict__ h0p, const float* __restrict__ Fb,
                      const float* __restrict__ Sb, float* __restrict__ Cin)
{
    const int idx = blockIdx.x * blockDim.x + threadIdx.x;  // 0..8191
    const int b = idx >> 10, h = idx & 1023;
    float carry = g_fn(h0p[(size_t)b * Hc + h]);
    for (int c = 0; c < NC2; c++) {
        size_t ci = ((size_t)b * NC2 + c) * Hc + h;
        Cin[ci] = carry;
        carry = fmaf(Fb[ci], carry, Sb[ci]);
    }
}

// pass C: apply carry, recompute f/v, write h (fp32 out)
__global__ __launch_bounds__(128) void scanC(const _Float16* __restrict__ k16,
                                             const _Float16* __restrict__ p16,
                                             const float* __restrict__ Cin,
                                             float* __restrict__ out)
{
    const int b = blockIdx.y, c = blockIdx.x;
    const int h0 = threadIdx.x * 8;
    size_t base = ((size_t)b * Tc + (size_t)c * L2c) * Hc + h0;
    size_t ci = ((size_t)b * NC2 + c) * Hc + h0;
    float hr[8];
#pragma unroll
    for (int j = 0; j < 8; j++) hr[j] = Cin[ci + j];
    for (int t = 0; t < L2c; t++) {
        half8_t k8 = *reinterpret_cast<const half8_t*>(k16 + base + (size_t)t * Hc);
        half8_t p8 = *reinterpret_cast<const half8_t*>(p16 + base + (size_t)t * Hc);
#pragma unroll
        for (int j = 0; j < 8; j++) {
            float f, v; fv_from_kp((float)k8[j], (float)p8[j], f, v);
            hr[j] = fmaf(f, hr[j], v);
        }
        float4 o0 = make_float4(hr[0], hr[1], hr[2], hr[3]);
        float4 o1 = make_float4(hr[4], hr[5], hr[6], hr[7]);
        *reinterpret_cast<float4*>(out + base + (size_t)t * Hc)     = o0;
        *reinterpret_cast<float4*>(out + base + (size_t)t * Hc + 4) = o1;
    }
}

// ---------------- launch ----------------
extern "C" void kernel_launch(void* const* d_in, const int* in_sizes, int n_in,
                              void* d_out, int out_size, void* d_ws, size_t ws_size,
                              hipStream_t stream)
{
    const float* x  = (const float*)d_in[0];
    const float* h0 = (const float*)d_in[1];
    const float* Wz = (const float*)d_in[2];
    const float* bz = (const float*)d_in[3];
    const float* Wh = (const float*)d_in[4];
    const float* bh = (const float*)d_in[5];
    float* out = (float*)d_out;

    char* ws = (char*)d_ws;
    // layout (bytes):
    //   x16   @ 0          (64 MB)
    //   w16z  @ 67108864   (2 MB)
    //   w16h  @ 69206016   (2 MB)
    //   k16   @ 71303168   (64 MB)
    //   p16   @ 138412032  (64 MB)
    //   Fb    @ 205520896  (4 MB)
    //   Sb    @ 209715200  (4 MB)
    //   Cin   @ 213909504  (4 MB)   total 208 MB
    _Float16* x16  = (_Float16*)ws;
    _Float16* w16z = (_Float16*)(ws + 67108864ULL);
    _Float16* w16h = (_Float16*)(ws + 69206016ULL);
    _Float16* k16  = (_Float16*)(ws + 71303168ULL);
    _Float16* p16  = (_Float16*)(ws + 138412032ULL);
    float* Fb  = (float*)(ws + 205520896ULL);
    float* Sb  = (float*)(ws + 209715200ULL);
    float* Cin = (float*)(ws + 213909504ULL);

    cvt_kernel<<<2048, 256, 0, stream>>>(x,  x16,  (long)Mc * Ic);
    cvt_kernel<<<256,  256, 0, stream>>>(Wz, w16z, (long)Hc * Ic);
    cvt_kernel<<<256,  256, 0, stream>>>(Wh, w16h, (long)Hc * Ic);

    dual_gemm_f16<<<2048, 512, 0, stream>>>(x16, w16z, w16h, bz, bh, k16, p16);

    dim3 sgrid(NC2, Bc);                 // (128, 8)
    scanA<<<sgrid, 128, 0, stream>>>(k16, p16, Fb, Sb);
    scanB<<<32, 256, 0, stream>>>(h0, Fb, Sb, Cin);
    scanC<<<sgrid, 128, 0, stream>>>(k16, p16, Cin, out);
}